// Round 4
// baseline (155.495 us; speedup 1.0000x reference)
//
#include <hip/hip_runtime.h>
#include <hip/hip_bf16.h>
#include <math.h>

// Dims: B=8, T=1048576, V=257, E=8, C=128, K=512, S=512, N=64
// GEMM view: M=16384, Kdim=4096, Ncols=256.
// Fully fused: col tile nt = [w1 ch 32nt..+32 | w2 ch 32nt..+32]; epilogue does
// bias+gate+patch-max in-register, writes d_out directly.
// R4: barrier-free main loop. B-fragments are loaded per-lane directly from
// Wp (2MB, L2-resident per XCD) into registers with a 2-deep rolling buffer
// over flat gt = sp*8+t; A-gathers (embl, 4KB LDS) roll 1-deep. No ldsB, no
// ds_write, no s_barrier in the loop -> LDS traffic halved, no barrier drain.
// Wave tile 64x64 (4rg x 4nf), BM=256, BN=64, grid 256 = 1 wave/SIMD; latency
// hidden purely by ILP (compiler's counted waitcnt, nothing defeats it).

typedef __bf16 bf16x8 __attribute__((ext_vector_type(8)));
typedef float  f32x4  __attribute__((ext_vector_type(4)));

// ---------------- ws layout ----------------
// [0, 2MB)    : Wp bf16 [nt=4][s'=16][t=8][q=4][n=64][e=8]  (byte = s'*32+q*8+t)
// [2MB, +8KB) : emb bf16 [257][8]
#define WS_WP_OFF   0
#define WS_EMB_OFF  (2u << 20)

// ---------------------------------------------------------------------------
// prep: coalesced LDS-transpose weight pack + emb bf16 table.
// cb = nt*2 + nhalf: nhalf=0 -> w1 channels [32nt,32nt+32), nhalf=1 -> w2 same.
// ---------------------------------------------------------------------------
__global__ void prep_kernel(const float* __restrict__ w1,
                            const float* __restrict__ w2,
                            const float* __restrict__ emb,
                            uint4* __restrict__ Wp4,
                            __bf16* __restrict__ embp) {
    int bid = blockIdx.x;
    int tid = threadIdx.x;
    if (bid < 128) {
        __shared__ __bf16 lds[8192];   // [(q*8+t)*32 + cl]*8 + e
        int cb = bid & 7;
        int sB = bid >> 3;
        int nt = cb >> 1, nhalf = cb & 1;
        const float* wsrc = (nhalf ? w2 : w1) + ((size_t)(nt << 5) << 12);
        int j4  = tid & 7;
        int pr0 = tid >> 3;
#pragma unroll
        for (int p = 0; p < 8; ++p) {
            int pair = p * 32 + pr0;          // 0..255 = (cl, e)
            int cl = pair >> 3, e = pair & 7;
            const float4 v = *(const float4*)(wsrc + ((size_t)cl << 12) + (e << 9) + (sB << 5) + (j4 << 2));
            float vv[4] = {v.x, v.y, v.z, v.w};
#pragma unroll
            for (int jj = 0; jj < 4; ++jj) {
                int j = (j4 << 2) + jj;        // byte_local
                int qq = j >> 3, tt = j & 7;
                lds[(((qq << 3) + tt) * 32 + cl) * 8 + e] = (__bf16)vv[jj];
            }
        }
        __syncthreads();
        const uint4* l4 = (const uint4*)lds;
        int base = (nt << 15) + (sB << 11) + (nhalf << 5);   // uint4 units
#pragma unroll
        for (int it = 0; it < 4; ++it) {
            int idx = it * 256 + tid;                         // 0..1023
            int qq = idx >> 8, tt = (idx >> 5) & 7, w = idx & 31;
            Wp4[base + (tt << 8) + (qq << 6) + w] = l4[idx];
        }
    } else {
        for (int i = tid; i < 2056; i += 256) embp[i] = (__bf16)emb[i];
    }
}

// ---------------------------------------------------------------------------
// gemm+epilogue: BM=256, BN=64, 4 waves, wave-tile 64x64 (4rg x 4nf), full K.
// B per-lane from global (L2): addr = Wp + nt*512K + gt*4096 + q*1024
//                                    + nf*256 + nl*16, gt = sp*8+t in [0,128).
// Rolling buffers: bb[2][4] refilled with gt+2 right after consumption;
// aa[2][4] gathers t+1 during t's MFMAs. Only barrier: one __syncthreads
// after the embl fill. Grid 256 = 64 mt x 4 nt; bid&7 = XCD (x panel + all
// Wp panels L2-shared per XCD).
// ---------------------------------------------------------------------------
__global__ __launch_bounds__(256, 1)
void gemm_kernel(const int* __restrict__ x,
                 const __bf16* __restrict__ Wp,
                 const uint4* __restrict__ embp,
                 const float* __restrict__ b1,
                 const float* __restrict__ b2,
                 float* __restrict__ out) {
    __shared__ uint4 embl[257];

    const int tid  = threadIdx.x;
    const int wave = tid >> 6;
    const int lane = tid & 63;
    const int q    = lane >> 4;
    const int nl   = lane & 15;

    for (int i = tid; i < 257; i += 256) embl[i] = embp[i];

    const int bid = blockIdx.x;
    const int mt = ((bid >> 5) << 3) | (bid & 7);   // 0..63
    const int nt = (bid >> 3) & 3;
    const int m0 = mt << 8;
    const int rA = m0 + (wave << 6) + nl;

    // per-lane flat B pointer: add gt*4096 + nf*256 per access
    const char* Bflat = (const char*)Wp + ((size_t)nt << 19) + (q << 10) + (nl << 4);

    const int* xp[4];
#pragma unroll
    for (int rg = 0; rg < 4; ++rg)
        xp[rg] = x + (size_t)(rA + (rg << 4)) * 512 + (q << 3);

    int4 xc[4][2];
#pragma unroll
    for (int rg = 0; rg < 4; ++rg) {
        xc[rg][0] = *(const int4*)xp[rg];
        xc[rg][1] = *(const int4*)(xp[rg] + 4);
    }

    // B register pipeline preload: gt = 0, 1
    bf16x8 bb[2][4];
#pragma unroll
    for (int nf = 0; nf < 4; ++nf) {
        bb[0][nf] = *reinterpret_cast<const bf16x8*>(Bflat + (nf << 8));
        bb[1][nf] = *reinterpret_cast<const bf16x8*>(Bflat + 4096 + (nf << 8));
    }

    __syncthreads();   // embl ready (one-time; no barriers after this)

    f32x4 acc[4][4] = {};

    for (int sp = 0; sp < 16; ++sp) {
        // extract this step's byte indices, then immediately re-issue xc
        // loads for sp+1 (HBM latency hidden under the whole step)
        int idx[4][8];
#pragma unroll
        for (int rg = 0; rg < 4; ++rg) {
            idx[rg][0] = xc[rg][0].x; idx[rg][1] = xc[rg][0].y;
            idx[rg][2] = xc[rg][0].z; idx[rg][3] = xc[rg][0].w;
            idx[rg][4] = xc[rg][1].x; idx[rg][5] = xc[rg][1].y;
            idx[rg][6] = xc[rg][1].z; idx[rg][7] = xc[rg][1].w;
        }
        if (sp < 15) {
#pragma unroll
            for (int rg = 0; rg < 4; ++rg) {
                const int* p = xp[rg] + ((sp + 1) << 5);
                xc[rg][0] = *(const int4*)p;
                xc[rg][1] = *(const int4*)(p + 4);
            }
        }

        // A pipeline: gather t=0
        bf16x8 aa[2][4];
#pragma unroll
        for (int rg = 0; rg < 4; ++rg)
            aa[0][rg] = *reinterpret_cast<const bf16x8*>(&embl[idx[rg][0]]);

#pragma unroll
        for (int t = 0; t < 8; ++t) {
            if (t < 7) {   // gather t+1 into the other slot
#pragma unroll
                for (int rg = 0; rg < 4; ++rg)
                    aa[(t + 1) & 1][rg] = *reinterpret_cast<const bf16x8*>(&embl[idx[rg][t + 1]]);
            }
#pragma unroll
            for (int nf = 0; nf < 4; ++nf) {
#pragma unroll
                for (int rg = 0; rg < 4; ++rg)
                    acc[rg][nf] = __builtin_amdgcn_mfma_f32_16x16x32_bf16(
                        aa[t & 1][rg], bb[t & 1][nf], acc[rg][nf], 0, 0, 0);
            }
            {   // refill the slot just consumed with gt+2
                int gt2 = (sp << 3) + t + 2;
                if (gt2 > 127) gt2 = 127;                  // harmless clamp
                const char* pb = Bflat + ((size_t)gt2 << 12);
#pragma unroll
                for (int nf = 0; nf < 4; ++nf)
                    bb[t & 1][nf] = *reinterpret_cast<const bf16x8*>(pb + (nf << 8));
            }
        }
    }

    // ---- fused epilogue ----
    // acc[rg][nf][i]: row = m0 + wave*64 + rg*16 + q*4 + i
    //   nf in {0,1}: c1 of channel ch = nt*32 + nf*16 + nl; nf+2: c2 of same ch.
    // patch (32 rows) = mt*8 + wave*2 + (rg>>1); per-lane max over (rg&1, i),
    // then shfl_xor 16/32 across q-groups.
    float bb1[2], bb2[2];
#pragma unroll
    for (int nf = 0; nf < 2; ++nf) {
        int ch = (nt << 5) + (nf << 4) + nl;
        bb1[nf] = b1[ch];
        bb2[nf] = b2[ch];
    }
#pragma unroll
    for (int ph = 0; ph < 2; ++ph) {
#pragma unroll
        for (int nf = 0; nf < 2; ++nf) {
            float v = -INFINITY;
#pragma unroll
            for (int rh = 0; rh < 2; ++rh) {
                int rg = (ph << 1) + rh;
#pragma unroll
                for (int i = 0; i < 4; ++i) {
                    float c1 = acc[rg][nf][i] + bb1[nf];
                    float c2 = acc[rg][nf + 2][i] + bb2[nf];
                    float g = c1 * (1.0f / (1.0f + __expf(-c2)));
                    v = fmaxf(v, g);
                }
            }
            v = fmaxf(v, __shfl_xor(v, 16));
            v = fmaxf(v, __shfl_xor(v, 32));
            if (lane < 16) {
                int P = (mt << 3) + (wave << 1) + ph;     // global patch id
                out[(size_t)P * 128 + (nt << 5) + (nf << 4) + nl] = v;
            }
        }
    }
}

// ---------------------------------------------------------------------------
extern "C" void kernel_launch(void* const* d_in, const int* in_sizes, int n_in,
                              void* d_out, int out_size, void* d_ws, size_t ws_size,
                              hipStream_t stream) {
    const int*   x   = (const int*)d_in[0];
    const float* emb = (const float*)d_in[1];
    const float* w1  = (const float*)d_in[2];
    const float* b1  = (const float*)d_in[3];
    const float* w2  = (const float*)d_in[4];
    const float* b2  = (const float*)d_in[5];
    float* out = (float*)d_out;

    char* ws = (char*)d_ws;
    __bf16* Wp   = (__bf16*)(ws + WS_WP_OFF);
    __bf16* embp = (__bf16*)(ws + WS_EMB_OFF);

    prep_kernel<<<129, 256, 0, stream>>>(w1, w2, emb, (uint4*)Wp, embp);
    gemm_kernel<<<256, 256, 0, stream>>>(x, Wp, (const uint4*)embp, b1, b2, out);
}

// Round 5
// 125.340 us; speedup vs baseline: 1.2406x; 1.2406x over previous
//
#include <hip/hip_runtime.h>
#include <hip/hip_bf16.h>
#include <math.h>

// Dims: B=8, T=1048576, V=257, E=8, C=128, K=512, S=512, N=64
// GEMM view: M=16384, Kdim=4096, Ncols=256.
// R5: K-split 8-wave blocks. Waves kh=0 compute K-steps 0..7, kh=1 steps
// 8..15 of the SAME four 64x64 wave tiles; acc merged once via LDS at the
// end. Main loop stays barrier-free (B per-lane direct from L2-resident Wp,
// 2-deep register pipeline; A-gathers from 4KB embl LDS). 2 waves/SIMD hide
// L2/HBM latency that killed R4 (1 wave/SIMD, 80us).

typedef __bf16 bf16x8 __attribute__((ext_vector_type(8)));
typedef float  f32x4  __attribute__((ext_vector_type(4)));

// ---------------- ws layout ----------------
// [0, 2MB)    : Wp bf16 [nt=4][s'=16][t=8][q=4][n=64][e=8]  (byte = s'*32+q*8+t)
// [2MB, +8KB) : emb bf16 [257][8]
#define WS_WP_OFF   0
#define WS_EMB_OFF  (2u << 20)

// ---------------------------------------------------------------------------
// prep: coalesced LDS-transpose weight pack + emb bf16 table.
// cb = nt*2 + nhalf: nhalf=0 -> w1 channels [32nt,32nt+32), nhalf=1 -> w2 same.
// ---------------------------------------------------------------------------
__global__ void prep_kernel(const float* __restrict__ w1,
                            const float* __restrict__ w2,
                            const float* __restrict__ emb,
                            uint4* __restrict__ Wp4,
                            __bf16* __restrict__ embp) {
    int bid = blockIdx.x;
    int tid = threadIdx.x;
    if (bid < 128) {
        __shared__ __bf16 lds[8192];   // [(q*8+t)*32 + cl]*8 + e
        int cb = bid & 7;
        int sB = bid >> 3;
        int nt = cb >> 1, nhalf = cb & 1;
        const float* wsrc = (nhalf ? w2 : w1) + ((size_t)(nt << 5) << 12);
        int j4  = tid & 7;
        int pr0 = tid >> 3;
#pragma unroll
        for (int p = 0; p < 8; ++p) {
            int pair = p * 32 + pr0;          // 0..255 = (cl, e)
            int cl = pair >> 3, e = pair & 7;
            const float4 v = *(const float4*)(wsrc + ((size_t)cl << 12) + (e << 9) + (sB << 5) + (j4 << 2));
            float vv[4] = {v.x, v.y, v.z, v.w};
#pragma unroll
            for (int jj = 0; jj < 4; ++jj) {
                int j = (j4 << 2) + jj;        // byte_local
                int qq = j >> 3, tt = j & 7;
                lds[(((qq << 3) + tt) * 32 + cl) * 8 + e] = (__bf16)vv[jj];
            }
        }
        __syncthreads();
        const uint4* l4 = (const uint4*)lds;
        int base = (nt << 15) + (sB << 11) + (nhalf << 5);   // uint4 units
#pragma unroll
        for (int it = 0; it < 4; ++it) {
            int idx = it * 256 + tid;                         // 0..1023
            int qq = idx >> 8, tt = (idx >> 5) & 7, w = idx & 31;
            Wp4[base + (tt << 8) + (qq << 6) + w] = l4[idx];
        }
    } else {
        for (int i = tid; i < 2056; i += 256) embp[i] = (__bf16)emb[i];
    }
}

// ---------------------------------------------------------------------------
// gemm+epilogue: 512 threads = 8 waves. rw = wave&3 picks the 64-row group,
// kh = wave>>2 picks the K half (steps kh*8 .. kh*8+8). Per wave: 64x64 tile
// (4rg x 4nf), B per-lane from global (addr = Wp + nt*512K + gt*4096 +
// q*1024 + nf*256 + nl*16, gt = sp*8+t), 2-deep bb pipeline, 1-deep aa
// gather pipeline, x prefetched one step ahead. No barriers in the loop.
// End: kh=1 waves dump acc to LDS (lane-contiguous, conflict-free b32),
// one __syncthreads, kh=0 waves add + bias/gate/patch-max -> out.
// Grid 256 = 64 mt x 4 nt; bid&7 = XCD (x panel + Wp L2-shared per XCD).
// ---------------------------------------------------------------------------
__global__ __launch_bounds__(512, 2)
void gemm_kernel(const int* __restrict__ x,
                 const __bf16* __restrict__ Wp,
                 const uint4* __restrict__ embp,
                 const float* __restrict__ b1,
                 const float* __restrict__ b2,
                 float* __restrict__ out) {
    __shared__ uint4 embl[257];
    __shared__ float mrg[4 * 64 * 64];   // [rw][r=rg*16+nf*4+i][lane]

    const int tid  = threadIdx.x;
    const int wave = tid >> 6;
    const int lane = tid & 63;
    const int q    = lane >> 4;
    const int nl   = lane & 15;
    const int rw   = wave & 3;
    const int kh   = wave >> 2;

    for (int i = tid; i < 257; i += 512) embl[i] = embp[i];

    const int bid = blockIdx.x;
    const int mt = ((bid >> 5) << 3) | (bid & 7);   // 0..63
    const int nt = (bid >> 3) & 3;
    const int m0 = mt << 8;
    const int rA = m0 + (rw << 6) + nl;

    // per-lane flat B pointer: add gt*4096 + nf*256 per access
    const char* Bflat = (const char*)Wp + ((size_t)nt << 19) + (q << 10) + (nl << 4);

    const int sp0 = kh << 3;
    const int spE = sp0 + 8;

    const int* xp[4];
#pragma unroll
    for (int rg = 0; rg < 4; ++rg)
        xp[rg] = x + (size_t)(rA + (rg << 4)) * 512 + (q << 3);

    int4 xc[4][2];
#pragma unroll
    for (int rg = 0; rg < 4; ++rg) {
        const int* p = xp[rg] + (sp0 << 5);
        xc[rg][0] = *(const int4*)p;
        xc[rg][1] = *(const int4*)(p + 4);
    }

    // B register pipeline preload: gt = kh*64, kh*64+1
    bf16x8 bb[2][4];
    {
        const char* pb0 = Bflat + ((size_t)(kh << 6) << 12);
#pragma unroll
        for (int nf = 0; nf < 4; ++nf) {
            bb[0][nf] = *reinterpret_cast<const bf16x8*>(pb0 + (nf << 8));
            bb[1][nf] = *reinterpret_cast<const bf16x8*>(pb0 + 4096 + (nf << 8));
        }
    }

    __syncthreads();   // embl ready (no barriers in main loop)

    f32x4 acc[4][4] = {};

    for (int sp = sp0; sp < spE; ++sp) {
        int idx[4][8];
#pragma unroll
        for (int rg = 0; rg < 4; ++rg) {
            idx[rg][0] = xc[rg][0].x; idx[rg][1] = xc[rg][0].y;
            idx[rg][2] = xc[rg][0].z; idx[rg][3] = xc[rg][0].w;
            idx[rg][4] = xc[rg][1].x; idx[rg][5] = xc[rg][1].y;
            idx[rg][6] = xc[rg][1].z; idx[rg][7] = xc[rg][1].w;
        }
        if (sp + 1 < spE) {   // x prefetch for next step
#pragma unroll
            for (int rg = 0; rg < 4; ++rg) {
                const int* p = xp[rg] + ((sp + 1) << 5);
                xc[rg][0] = *(const int4*)p;
                xc[rg][1] = *(const int4*)(p + 4);
            }
        }

        // A pipeline: gather t=0
        bf16x8 aa[2][4];
#pragma unroll
        for (int rg = 0; rg < 4; ++rg)
            aa[0][rg] = *reinterpret_cast<const bf16x8*>(&embl[idx[rg][0]]);

#pragma unroll
        for (int t = 0; t < 8; ++t) {
            if (t < 7) {   // gather t+1 into the other slot
#pragma unroll
                for (int rg = 0; rg < 4; ++rg)
                    aa[(t + 1) & 1][rg] = *reinterpret_cast<const bf16x8*>(&embl[idx[rg][t + 1]]);
            }
#pragma unroll
            for (int nf = 0; nf < 4; ++nf) {
#pragma unroll
                for (int rg = 0; rg < 4; ++rg)
                    acc[rg][nf] = __builtin_amdgcn_mfma_f32_16x16x32_bf16(
                        aa[t & 1][rg], bb[t & 1][nf], acc[rg][nf], 0, 0, 0);
            }
            {   // refill the slot just consumed with gt+2
                int gt2 = (sp << 3) + t + 2;
                if (gt2 > 127) gt2 = 127;                  // harmless clamp
                const char* pb = Bflat + ((size_t)gt2 << 12);
#pragma unroll
                for (int nf = 0; nf < 4; ++nf)
                    bb[t & 1][nf] = *reinterpret_cast<const bf16x8*>(pb + (nf << 8));
            }
        }
    }

    // ---- K-half merge ----
    if (kh == 1) {
#pragma unroll
        for (int rg = 0; rg < 4; ++rg)
#pragma unroll
            for (int nf = 0; nf < 4; ++nf)
#pragma unroll
                for (int i = 0; i < 4; ++i) {
                    int r = (rg << 4) + (nf << 2) + i;
                    mrg[(((rw << 6) + r) << 6) + lane] = acc[rg][nf][i];
                }
    }
    __syncthreads();
    if (kh == 1) return;

#pragma unroll
    for (int rg = 0; rg < 4; ++rg)
#pragma unroll
        for (int nf = 0; nf < 4; ++nf)
#pragma unroll
            for (int i = 0; i < 4; ++i) {
                int r = (rg << 4) + (nf << 2) + i;
                acc[rg][nf][i] += mrg[(((rw << 6) + r) << 6) + lane];
            }

    // ---- fused epilogue (kh=0 waves) ----
    // acc[rg][nf][i]: row = m0 + rw*64 + rg*16 + q*4 + i
    //   nf in {0,1}: c1 of channel ch = nt*32 + nf*16 + nl; nf+2: c2 of same ch.
    // patch (32 rows) = mt*8 + rw*2 + (rg>>1); per-lane max over (rg&1, i),
    // then shfl_xor 16/32 across q-groups.
    float bb1[2], bb2[2];
#pragma unroll
    for (int nf = 0; nf < 2; ++nf) {
        int ch = (nt << 5) + (nf << 4) + nl;
        bb1[nf] = b1[ch];
        bb2[nf] = b2[ch];
    }
#pragma unroll
    for (int ph = 0; ph < 2; ++ph) {
#pragma unroll
        for (int nf = 0; nf < 2; ++nf) {
            float v = -INFINITY;
#pragma unroll
            for (int rh = 0; rh < 2; ++rh) {
                int rg = (ph << 1) + rh;
#pragma unroll
                for (int i = 0; i < 4; ++i) {
                    float c1 = acc[rg][nf][i] + bb1[nf];
                    float c2 = acc[rg][nf + 2][i] + bb2[nf];
                    float g = c1 * (1.0f / (1.0f + __expf(-c2)));
                    v = fmaxf(v, g);
                }
            }
            v = fmaxf(v, __shfl_xor(v, 16));
            v = fmaxf(v, __shfl_xor(v, 32));
            if (lane < 16) {
                int P = (mt << 3) + (rw << 1) + ph;       // global patch id
                out[(size_t)P * 128 + (nt << 5) + (nf << 4) + nl] = v;
            }
        }
    }
}

// ---------------------------------------------------------------------------
extern "C" void kernel_launch(void* const* d_in, const int* in_sizes, int n_in,
                              void* d_out, int out_size, void* d_ws, size_t ws_size,
                              hipStream_t stream) {
    const int*   x   = (const int*)d_in[0];
    const float* emb = (const float*)d_in[1];
    const float* w1  = (const float*)d_in[2];
    const float* b1  = (const float*)d_in[3];
    const float* w2  = (const float*)d_in[4];
    const float* b2  = (const float*)d_in[5];
    float* out = (float*)d_out;

    char* ws = (char*)d_ws;
    __bf16* Wp   = (__bf16*)(ws + WS_WP_OFF);
    __bf16* embp = (__bf16*)(ws + WS_EMB_OFF);

    prep_kernel<<<129, 256, 0, stream>>>(w1, w2, emb, (uint4*)Wp, embp);
    gemm_kernel<<<256, 512, 0, stream>>>(x, Wp, (const uint4*)embp, b1, b2, out);
}